// Round 6
// baseline (300.771 us; speedup 1.0000x reference)
//
#include <hip/hip_runtime.h>

typedef short bf16x8 __attribute__((ext_vector_type(8)));
typedef float f32x4 __attribute__((ext_vector_type(4)));
typedef unsigned short ushort8 __attribute__((ext_vector_type(8)));
typedef unsigned short ushort4v __attribute__((ext_vector_type(4)));

#define BATCH 16
#define DCAT 512
#define CIN 256
#define COUT 256
#define HH 64
#define WW 64

__device__ __forceinline__ unsigned short f2bf(float f) {
  unsigned int u = __float_as_uint(f);
  unsigned int r = (u + 0x7fffu + ((u >> 16) & 1u)) >> 16;
  return (unsigned short)r;
}

// ---------------- fused style-MLP (3 layers) + conv-weight repack.
// blocks [0,16): per-batch 3-layer EqualLinear MLP -> sbuf (16x256 f32).
//   16 waves/block; wave wv computes outputs c = wv*16 + 0..15 per layer.
// blocks [16,160): conv_w (O,I,3,3) fp32 -> wt[tap][o][i] bf16 (tap-major).
__global__ void __launch_bounds__(1024) mlp_wt(const float* __restrict__ y,
                                               const float* __restrict__ w0,
                                               const float* __restrict__ b0,
                                               const float* __restrict__ w1,
                                               const float* __restrict__ b1,
                                               const float* __restrict__ w2,
                                               const float* __restrict__ b2,
                                               const float* __restrict__ cw,
                                               float* __restrict__ sbuf,
                                               unsigned short* __restrict__ wt) {
  int tid = threadIdx.x, blk = blockIdx.x;

  if (blk >= 16) {  // ---- wt repack: 144 blocks x 1024 = 147456 threads
    int idx = (blk - 16) * 1024 + tid;
    int t = idx / 16384;
    int r = idx - t * 16384;  // o*64 + i4
    int o = r >> 6, i4 = r & 63;
    ushort4v v;
#pragma unroll
    for (int j = 0; j < 4; j++) v[j] = f2bf(cw[(o * 256 + i4 * 4 + j) * 9 + t]);
    *(ushort4v*)(wt + ((size_t)(t * COUT + o)) * CIN + i4 * 4) = v;
    return;
  }

  // ---- MLP part: b = blk
  __shared__ float t0s[256], t1s[256];
  int wv = tid >> 6, lane = tid & 63;

  // layer 1: 512 -> 256
  float yv[8];
#pragma unroll
  for (int j = 0; j < 8; j++) yv[j] = y[blk * DCAT + lane * 8 + j];
  for (int i = 0; i < 16; i++) {
    int c = wv * 16 + i;
    const float* wr = w0 + (size_t)c * DCAT + lane * 8;
    float sum = 0.f;
#pragma unroll
    for (int j = 0; j < 8; j++) sum += wr[j] * yv[j];
#pragma unroll
    for (int off = 32; off; off >>= 1) sum += __shfl_xor(sum, off, 64);
    if (lane == 0) {
      float a = sum + b0[c];
      t0s[c] = a >= 0.f ? a : 0.01f * a;
    }
  }
  __syncthreads();

  // layer 2: 256 -> 256
  float tv[4];
#pragma unroll
  for (int j = 0; j < 4; j++) tv[j] = t0s[lane * 4 + j];
  for (int i = 0; i < 16; i++) {
    int c = wv * 16 + i;
    const float* wr = w1 + (size_t)c * CIN + lane * 4;
    float sum = 0.f;
#pragma unroll
    for (int j = 0; j < 4; j++) sum += wr[j] * tv[j];
#pragma unroll
    for (int off = 32; off; off >>= 1) sum += __shfl_xor(sum, off, 64);
    if (lane == 0) {
      float a = sum + b1[c];
      t1s[c] = a >= 0.f ? a : 0.01f * a;
    }
  }
  __syncthreads();

  // layer 3: 256 -> 256 -> sbuf
  float uv[4];
#pragma unroll
  for (int j = 0; j < 4; j++) uv[j] = t1s[lane * 4 + j];
  for (int i = 0; i < 16; i++) {
    int c = wv * 16 + i;
    const float* wr = w2 + (size_t)c * CIN + lane * 4;
    float sum = 0.f;
#pragma unroll
    for (int j = 0; j < 4; j++) sum += wr[j] * uv[j];
#pragma unroll
    for (int off = 32; off; off >>= 1) sum += __shfl_xor(sum, off, 64);
    if (lane == 0) {
      float a = sum + b2[c];
      sbuf[blk * 256 + c] = a >= 0.f ? a : 0.01f * a;
    }
  }
}

// ---------------- fused implicit-GEMM conv: BM=128 px, BN=256 out, BK=64.
// R0 loop/MFMA/epilogue verbatim, but the A operand is staged DIRECTLY from
// x (NCHW fp32): 16 per-e-coalesced loads/thread/step, clamp+mask for the
// zero border, multiply by wave-uniform style s, f2bf, ds_write_b128 into
// the same XOR-swizzled As layout (reg-staged writes may swizzle; the
// read-side XOR is unchanged). kc2 is the OUTER loop so each wave's 8 style
// scalars stay in 8 registers. B stays global_load_lds from tap-major wt.
// This deletes the xpad tensor (36 MB write + reads) and the prep kernel.
__device__ __forceinline__ void gl2lds16(const void* g, void* l) {
  __builtin_amdgcn_global_load_lds((const __attribute__((address_space(1))) void*)g,
                                   (__attribute__((address_space(3))) void*)l, 16, 0, 0);
}

__global__ void __launch_bounds__(512, 4) gemm_conv(const float* __restrict__ x,
                                                    const float* __restrict__ sbuf,
                                                    const unsigned short* __restrict__ wt,
                                                    float* __restrict__ out) {
  __shared__ unsigned short As[128 * 64];  // [pixel][64ch], XOR-swizzled chunks
  __shared__ unsigned short Bs[256 * 64];  // [o][64ch]
  int tid = threadIdx.x;
  int wid = tid >> 6, lane = tid & 63;
  int bid = blockIdx.x;
  // XCD swizzle: XCD x covers m_t in [x*64, x*64+64) = 2 contiguous images.
  int m_t = (bid & 7) * 64 + (bid >> 3);
  int m0 = m_t << 7;
  int b = m0 >> 12;
  int h0 = (m0 >> 6) & 63;           // tile covers image rows h0, h0+1
  int wm = wid & 1, wn = wid >> 1;   // 2x4 wave grid, each wave 64x64

  f32x4 acc[4][4];
#pragma unroll
  for (int mi = 0; mi < 4; mi++)
#pragma unroll
    for (int ni = 0; ni < 4; ni++) acc[mi][ni] = (f32x4){0.f, 0.f, 0.f, 0.f};

  // ---- A stager: thread = (pixel-col p = lane, chunk cg = wid).
  // Writes rows p (image row h0) and p+64 (row h0+1), slot cg^(p&7).
  int p = lane;
  char* wA0 = (char*)As + p * 128 + ((wid ^ (p & 7)) * 16);
  char* wA1 = wA0 + 64 * 128;
  const float* xb = x + (size_t)b * CIN * (HH * WW);

  // ---- B stager (R0 verbatim)
  int o_l = tid >> 3;
  int csb = tid & 7;
  const unsigned short* bL = wt + o_l * CIN + (csb ^ (o_l & 7)) * 8;
  char* Bs_w0 = (char*)Bs + wid * 1024;
  char* Bs_w1 = (char*)Bs + 8192 + wid * 1024;
  char* Bs_w2 = (char*)Bs + 16384 + wid * 1024;
  char* Bs_w3 = (char*)Bs + 24576 + wid * 1024;

  // ---- reader frag offsets (R0 verbatim)
  int rA = wm * 64 + (lane & 15);
  int rB = wn * 64 + (lane & 15);
  int qa = lane >> 4;
  int offA0 = rA * 128 + ((qa ^ (rA & 7)) * 16);
  int offA1 = rA * 128 + (((qa + 4) ^ (rA & 7)) * 16);
  int offB0 = rB * 128 + ((qa ^ (rB & 7)) * 16);
  int offB1 = rB * 128 + (((qa + 4) ^ (rB & 7)) * 16);

  for (int kc2 = 0; kc2 < 4; kc2++) {
    // wave-uniform style scalars for this kc2 phase (8 regs)
    float s8[8];
#pragma unroll
    for (int e = 0; e < 8; e++) s8[e] = sbuf[b * 256 + kc2 * 64 + wid * 8 + e];
    const float* xc = xb + (size_t)(kc2 * 64 + wid * 8) * (HH * WW);

    for (int kh = 0; kh < 3; kh++) {
      for (int kw = 0; kw < 3; kw++) {
        // B stage (fire-and-forget)
        const unsigned short* bG = bL + (kh * 3 + kw) * (COUT * CIN) + kc2 * 64;
        gl2lds16(bG, Bs_w0);
        gl2lds16(bG + 64 * CIN, Bs_w1);
        gl2lds16(bG + 128 * CIN, Bs_w2);
        gl2lds16(bG + 192 * CIN, Bs_w3);

        // A stage: 2 pixels x 8 channels, clamp+mask the zero border
        int sr0 = h0 + kh - 1, sr1 = sr0 + 1, sc = p + kw - 1;
        bool vr0 = (unsigned)sr0 < 64u, vr1 = (unsigned)sr1 < 64u;
        bool vcc = (unsigned)sc < 64u;
        int sra0 = sr0 < 0 ? 0 : (sr0 > 63 ? 63 : sr0);
        int sra1 = sr1 < 0 ? 0 : (sr1 > 63 ? 63 : sr1);
        int sca = sc < 0 ? 0 : (sc > 63 ? 63 : sc);
        const float* a0 = xc + sra0 * WW + sca;
        const float* a1 = xc + sra1 * WW + sca;
        bool m0v = vr0 && vcc, m1v = vr1 && vcc;
        ushort8 o0, o1;
#pragma unroll
        for (int e = 0; e < 8; e++) {
          float v0 = a0[e * (HH * WW)];
          float v1 = a1[e * (HH * WW)];
          o0[e] = f2bf((m0v ? v0 : 0.f) * s8[e]);
          o1[e] = f2bf((m1v ? v1 : 0.f) * s8[e]);
        }
        *(ushort8*)wA0 = o0;
        *(ushort8*)wA1 = o1;

        __syncthreads();
#pragma unroll
        for (int kb = 0; kb < 2; kb++) {
          int oa = kb ? offA1 : offA0;
          int ob = kb ? offB1 : offB0;
          bf16x8 av[4], bv[4];
#pragma unroll
          for (int mi = 0; mi < 4; mi++)
            av[mi] = *(const bf16x8*)((const char*)As + oa + mi * 2048);
#pragma unroll
          for (int ni = 0; ni < 4; ni++)
            bv[ni] = *(const bf16x8*)((const char*)Bs + ob + ni * 2048);
#pragma unroll
          for (int mi = 0; mi < 4; mi++)
#pragma unroll
            for (int ni = 0; ni < 4; ni++)
              acc[mi][ni] = __builtin_amdgcn_mfma_f32_16x16x32_bf16(av[mi], bv[ni],
                                                                    acc[mi][ni], 0, 0, 0);
        }
        __syncthreads();
      }
    }
  }

  // ---- epilogue (R0 verbatim): D row = pixel (quad*4+reg), col = o (lane&15)
  int pixbase = m0 & 4095;
  int quad = lane >> 4;
  int col = lane & 15;
#pragma unroll
  for (int mi = 0; mi < 4; mi++) {
    int pm = pixbase + wm * 64 + mi * 16 + quad * 4;
#pragma unroll
    for (int ni = 0; ni < 4; ni++) {
      int on = wn * 64 + ni * 16 + col;
      float* op = out + ((size_t)(b * COUT + on) << 12) + pm;
      *(f32x4*)op = acc[mi][ni];
    }
  }
}

extern "C" void kernel_launch(void* const* d_in, const int* in_sizes, int n_in,
                              void* d_out, int out_size, void* d_ws, size_t ws_size,
                              hipStream_t stream) {
  const float* x = (const float*)d_in[0];
  const float* y = (const float*)d_in[1];
  const float* w0 = (const float*)d_in[2];
  const float* b0 = (const float*)d_in[3];
  const float* w1 = (const float*)d_in[4];
  const float* b1 = (const float*)d_in[5];
  const float* w2 = (const float*)d_in[6];
  const float* b2 = (const float*)d_in[7];
  const float* cw = (const float*)d_in[8];
  float* out = (float*)d_out;

  char* ws = (char*)d_ws;
  float* sbuf = (float*)ws;                            // 16 KiB (16x256 styles)
  unsigned short* wt = (unsigned short*)(ws + 16384);  // 1.125 MiB

  mlp_wt<<<160, 1024, 0, stream>>>(y, w0, b0, w1, b1, w2, b2, cw, sbuf, wt);
  gemm_conv<<<BATCH * HH * WW / 128, 512, 0, stream>>>(x, sbuf, wt, out);
}

// Round 7
// 199.020 us; speedup vs baseline: 1.5113x; 1.5113x over previous
//
#include <hip/hip_runtime.h>

typedef short bf16x8 __attribute__((ext_vector_type(8)));
typedef float f32x4 __attribute__((ext_vector_type(4)));
typedef unsigned short ushort8 __attribute__((ext_vector_type(8)));
typedef unsigned short ushort4v __attribute__((ext_vector_type(4)));

#define BATCH 16
#define DCAT 512
#define CIN 256
#define COUT 256
#define HH 64
#define WW 64
#define HP 66
#define WP 66
#define PLANE (HP * WP * 8)  // shorts per c8-plane
#define AHALO 52224          // 408 entries (6 rows x 68 cols) * 128B
#define BBUF 32768

__device__ __forceinline__ unsigned short f2bf(float f) {
  unsigned int u = __float_as_uint(f);
  unsigned int r = (u + 0x7fffu + ((u >> 16) & 1u)) >> 16;
  return (unsigned short)r;
}

// ---------------- MLP layer: one wave per output element (b,c).
template <int IN_DIM>
__global__ void __launch_bounds__(256) mlp_layer(const float* __restrict__ in,
                                                 const float* __restrict__ w,
                                                 const float* __restrict__ bias,
                                                 float* __restrict__ out) {
  int wid = threadIdx.x >> 6, lane = threadIdx.x & 63;
  int oidx = blockIdx.x * 4 + wid;  // (b<<8)|c
  int b = oidx >> 8, c = oidx & 255;
  const float* wr = w + (size_t)c * IN_DIM;
  const float* ir = in + (size_t)b * IN_DIM;
  float sum = 0.f;
#pragma unroll
  for (int d0 = 0; d0 < IN_DIM; d0 += 256) {
    f32x4 wv = *(const f32x4*)(wr + d0 + lane * 4);
    f32x4 iv = *(const f32x4*)(ir + d0 + lane * 4);
    sum += wv[0] * iv[0] + wv[1] * iv[1] + wv[2] * iv[2] + wv[3] * iv[3];
  }
#pragma unroll
  for (int off = 32; off; off >>= 1) sum += __shfl_xor(sum, off, 64);
  if (lane == 0) {
    float a = sum + bias[c];
    out[oidx] = a >= 0.f ? a : 0.01f * a;
  }
}

// ---------------- consolidated prep (tap-major wt): R0-verbatim.
__global__ void __launch_bounds__(256) prep_all(const float* __restrict__ t1,
                                                const float* __restrict__ w2,
                                                const float* __restrict__ b2,
                                                const float* __restrict__ x,
                                                const float* __restrict__ cw,
                                                unsigned short* __restrict__ xpad,
                                                unsigned short* __restrict__ wt) {
  int blk = blockIdx.x;
  int tid = threadIdx.x;

  if (blk >= 1024) {  // ---- prep_w part
    int idx = (blk - 1024) * 256 + tid;  // 9*256*64 = 147456 threads
    int t = idx / 16384;
    int r = idx - t * 16384;  // o*64 + i4
    int o = r >> 6, i4 = r & 63;
    ushort4v v;
#pragma unroll
    for (int j = 0; j < 4; j++) v[j] = f2bf(cw[(o * 256 + i4 * 4 + j) * 9 + t]);
    *(ushort4v*)(wt + ((size_t)(t * COUT + o)) * CIN + i4 * 4) = v;
    return;
  }

  // ---- prep_x part: blk = (b<<6) | (c8<<1) | h
  int h = blk & 1, c8 = (blk >> 1) & 31, b = blk >> 6;
  int wid = tid >> 6, lane = tid & 63;

  float tv = t1[b * CIN + tid];
  float pj[8];
#pragma unroll
  for (int j = 0; j < 8; j++) pj[j] = w2[(size_t)(c8 * 8 + j) * CIN + tid] * tv;

  const float* xb = x + ((size_t)(b * CIN + c8 * 8)) * (HH * WW);
  int gg0 = h * 512 + tid;
  int gg1 = gg0 + 256;
  int hh0 = (gg0 >> 4) + 1, w00 = (gg0 & 15) * 4 + 1;
  int hh1 = (gg1 >> 4) + 1, w01 = (gg1 & 15) * 4 + 1;
  int base0 = (hh0 - 1) * WW + (w00 - 1);
  int base1 = (hh1 - 1) * WW + (w01 - 1);
  f32x4 v0[8], v1[8];
#pragma unroll
  for (int j = 0; j < 8; j++) v0[j] = *(const f32x4*)(xb + j * (HH * WW) + base0);
#pragma unroll
  for (int j = 0; j < 8; j++) v1[j] = *(const f32x4*)(xb + j * (HH * WW) + base1);

#pragma unroll
  for (int off = 32; off; off >>= 1)
#pragma unroll
    for (int j = 0; j < 8; j++) pj[j] += __shfl_xor(pj[j], off, 64);
  __shared__ float red[4][8];
  __shared__ float sv_sh[8];
  if (lane == 0)
#pragma unroll
    for (int j = 0; j < 8; j++) red[wid][j] = pj[j];
  __syncthreads();
  if (tid < 8) {
    float a = red[0][tid] + red[1][tid] + red[2][tid] + red[3][tid] + b2[c8 * 8 + tid];
    sv_sh[tid] = a >= 0.f ? a : 0.01f * a;
  }
  __syncthreads();
  float sv[8];
#pragma unroll
  for (int j = 0; j < 8; j++) sv[j] = sv_sh[j];

  unsigned short* xp = xpad + ((size_t)(b * 32 + c8)) * PLANE;

  if (tid < 130) {
    int i = h * 130 + tid;
    int bh, bw;
    if (i < 66) { bh = 0; bw = i; }
    else if (i < 132) { bh = 65; bw = i - 66; }
    else if (i < 196) { bh = i - 132 + 1; bw = 0; }
    else { bh = i - 196 + 1; bw = 65; }
    ushort8 z = {0, 0, 0, 0, 0, 0, 0, 0};
    *(ushort8*)(xp + (bh * WP + bw) * 8) = z;
  }

  unsigned short* op0 = xp + (hh0 * WP + w00) * 8;
  unsigned short* op1 = xp + (hh1 * WP + w01) * 8;
#pragma unroll
  for (int t2 = 0; t2 < 4; t2++) {
    ushort8 o;
#pragma unroll
    for (int j = 0; j < 8; j++) o[j] = f2bf(v0[j][t2] * sv[j]);
    *(ushort8*)(op0 + t2 * 8) = o;
  }
#pragma unroll
  for (int t2 = 0; t2 < 4; t2++) {
    ushort8 o;
#pragma unroll
    for (int j = 0; j < 8; j++) o[j] = f2bf(v1[j][t2] * sv[j]);
    *(ushort8*)(op1 + t2 * 8) = o;
  }
}

// ---------------- implicit-GEMM conv with tap-reuse: BM=256 px, BN=256 out.
// Per kc2 (64-ch slice): stage the A halo ONCE (6 rows x 68 cols x 64ch,
// 52 KB, entries of 128B = 64ch, XOR-chunk-swizzled), then 9 taps of
// {issue next-B stage -> ds_read shifted A window + B -> 64 MFMA/wave ->
// __syncthreads}. B double-buffered (2x32 KB); each tap's B prefetch has a
// full MFMA phase of cover before the barrier drain. A stage traffic /9.
__device__ __forceinline__ void gl2lds16(const void* g, void* l) {
  __builtin_amdgcn_global_load_lds((const __attribute__((address_space(1))) void*)g,
                                   (__attribute__((address_space(3))) void*)l, 16, 0, 0);
}

__global__ void __launch_bounds__(512, 1) gemm_conv(const unsigned short* __restrict__ xpad,
                                                    const unsigned short* __restrict__ wt,
                                                    float* __restrict__ out) {
  // LDS: A halo [0, 52224), B buf0 [52224, +32K), B buf1 [84992, +32K)
  __shared__ __align__(16) char lds[AHALO + 2 * BBUF];
  int tid = threadIdx.x;
  int wid = tid >> 6, lane = tid & 63;
  int bid = blockIdx.x;
  // XCD swizzle: 256 blocks, 32 contiguous tiles (=2 images) per XCD.
  int m_t = (bid & 7) * 32 + (bid >> 3);
  int m0 = m_t << 8;                 // first pixel of tile (BM=256 = 4 image rows)
  int b = m0 >> 12;
  int h0 = (m0 >> 6) & 63;           // tile covers image rows h0..h0+3
  int wm = wid & 1, wn = wid >> 1;   // 2x4 wave grid, each wave 128x64

  f32x4 acc[8][4];
#pragma unroll
  for (int mi = 0; mi < 8; mi++)
#pragma unroll
    for (int ni = 0; ni < 4; ni++) acc[mi][ni] = (f32x4){0.f, 0.f, 0.f, 0.f};

  // ---- A halo stager invariants: 51 wave-ops = 7 iters x 8 waves (wid<3 at i=6).
  // chunk-load c = (i*8+wid)*64 + lane; entry e = c>>3 (halo row e/68, col e%68),
  // slot cs = c&7 holds global chunk gs = cs ^ (e&7). Halo row 0 = image row
  // h0-1 = padded row h0; halo col 0 = image col -1 = padded col 0.
  const unsigned short* aSrc[7];
#pragma unroll
  for (int i = 0; i < 7; i++) {
    int c = (i * 8 + wid) * 64 + lane;
    int e = c >> 3, cs = c & 7;
    int gs = cs ^ (e & 7);
    int rh = e / 68, wc = e - rh * 68;
    aSrc[i] = xpad + ((size_t)((b * 32 + gs) * HP + (h0 + rh))) * (WP * 8) + wc * 8;
  }

  // ---- B stager invariants (R0-verbatim addressing)
  int o_l = tid >> 3;
  int csb = tid & 7;
  const unsigned short* bL = wt + o_l * CIN + ((csb ^ (o_l & 7)) * 8);

  // ---- reader invariants
  int qa = lane >> 4;
  int l15 = lane & 15;
  int rB = wn * 64 + l15;
  int offB0 = rB * 128 + ((qa ^ (rB & 7)) * 16);
  int offB1 = rB * 128 + (((qa + 4) ^ (rB & 7)) * 16);

  int cur = 0;
  for (int kc2 = 0; kc2 < 4; kc2++) {
    // ---- stage A halo for this kc2 (once), plus tap-0 B into buf[cur]
    size_t kofs = (size_t)kc2 * 8 * PLANE;  // shorts: +8 c8-planes
#pragma unroll
    for (int i = 0; i < 6; i++)
      gl2lds16(aSrc[i] + kofs, lds + (i * 8 + wid) * 1024);
    if (wid < 3) gl2lds16(aSrc[6] + kofs, lds + (48 + wid) * 1024);
    {
      const unsigned short* bG = bL + kc2 * 64;  // tap 0
      char* dB = lds + AHALO + cur * BBUF + wid * 1024;
#pragma unroll
      for (int q = 0; q < 4; q++) gl2lds16(bG + q * 64 * CIN, dB + q * 8192);
    }
    __syncthreads();  // drains vmcnt(0): A halo + B0 resident

    for (int kh = 0; kh < 3; kh++) {
      for (int kw = 0; kw < 3; kw++) {
        int tap = kh * 3 + kw;
        // issue next tap's B stage (full-MFMA-phase cover before the drain)
        if (tap < 8) {
          const unsigned short* bG = bL + (tap + 1) * (COUT * CIN) + kc2 * 64;
          char* dB = lds + AHALO + (cur ^ 1) * BBUF + wid * 1024;
#pragma unroll
          for (int q = 0; q < 4; q++) gl2lds16(bG + q * 64 * CIN, dB + q * 8192);
        }

        // A window offsets for this tap (XOR-swizzle re-based: 68 ≡ 4 mod 8)
        int eb = (wm * 2 + kh) * 68 + l15 + kw;
        int s0 = eb & 7, s1 = (eb + 4) & 7;
        int a00 = eb * 128 + ((qa ^ s0) * 16);
        int a01 = (eb + 68) * 128 + ((qa ^ s1) * 16);
        int a10 = eb * 128 + (((qa + 4) ^ s0) * 16);
        int a11 = (eb + 68) * 128 + (((qa + 4) ^ s1) * 16);
        const char* Bb = lds + AHALO + cur * BBUF;

#pragma unroll
        for (int kb = 0; kb < 2; kb++) {
          int oa0 = kb ? a10 : a00;
          int oa1 = kb ? a11 : a01;
          int ob = kb ? offB1 : offB0;
          bf16x8 av[8], bv[4];
#pragma unroll
          for (int mi = 0; mi < 4; mi++) {
            av[mi] = *(const bf16x8*)(lds + oa0 + mi * 2048);
            av[4 + mi] = *(const bf16x8*)(lds + oa1 + mi * 2048);
          }
#pragma unroll
          for (int ni = 0; ni < 4; ni++)
            bv[ni] = *(const bf16x8*)(Bb + ob + ni * 2048);
          __builtin_amdgcn_s_setprio(1);
#pragma unroll
          for (int mi = 0; mi < 8; mi++)
#pragma unroll
            for (int ni = 0; ni < 4; ni++)
              acc[mi][ni] = __builtin_amdgcn_mfma_f32_16x16x32_bf16(av[mi], bv[ni],
                                                                    acc[mi][ni], 0, 0, 0);
          __builtin_amdgcn_s_setprio(0);
        }

        __syncthreads();  // implicit vmcnt(0): next-B landed under MFMA cover
        cur ^= 1;
      }
    }
  }

  // ---- epilogue (R4-verbatim): D row = pixel (quad*4+reg), col = o (lane&15)
  int pixbase = m0 & 4095;
  int quad = lane >> 4;
  int col = lane & 15;
#pragma unroll
  for (int mi = 0; mi < 8; mi++) {
    int pm = pixbase + wm * 128 + mi * 16 + quad * 4;
#pragma unroll
    for (int ni = 0; ni < 4; ni++) {
      int on = wn * 64 + ni * 16 + col;
      float* op = out + ((size_t)(b * COUT + on) << 12) + pm;
      *(f32x4*)op = acc[mi][ni];
    }
  }
}

extern "C" void kernel_launch(void* const* d_in, const int* in_sizes, int n_in,
                              void* d_out, int out_size, void* d_ws, size_t ws_size,
                              hipStream_t stream) {
  const float* x = (const float*)d_in[0];
  const float* y = (const float*)d_in[1];
  const float* w0 = (const float*)d_in[2];
  const float* b0 = (const float*)d_in[3];
  const float* w1 = (const float*)d_in[4];
  const float* b1 = (const float*)d_in[5];
  const float* w2 = (const float*)d_in[6];
  const float* b2 = (const float*)d_in[7];
  const float* cw = (const float*)d_in[8];
  float* out = (float*)d_out;

  // xpad FIRST so the A-halo's 32B tail over-read lands in wt, inside ws.
  char* ws = (char*)d_ws;
  unsigned short* xpad = (unsigned short*)ws;                   // 35,684,352 B
  unsigned short* wt = (unsigned short*)(ws + 35684352);        // 2,359,296 B
  float* t0 = (float*)(ws + 35684352 + 2359296);                // 16 KiB
  float* t1 = (float*)(ws + 35684352 + 2359296 + 16384);        // 16 KiB

  mlp_layer<DCAT><<<BATCH * CIN / 4, 256, 0, stream>>>(y, w0, b0, t0);
  mlp_layer<CIN><<<BATCH * CIN / 4, 256, 0, stream>>>(t0, w1, b1, t1);
  prep_all<<<1024 + 576, 256, 0, stream>>>(t1, w2, b2, x, cw, xpad, wt);
  gemm_conv<<<BATCH * HH * WW / 256, 512, 0, stream>>>(xpad, wt, out);
}